// Round 12
// baseline (138.291 us; speedup 1.0000x reference)
//
#include <hip/hip_runtime.h>
#include <stdint.h>

#define DIM   128
#define NK    512
#define SPB   32768
#define NBLK  4096

#define E_OFF 16777216
#define D_OFF 83886080
#define L_OFF 150994944

typedef __attribute__((ext_vector_type(16))) float f32x16;
typedef __attribute__((ext_vector_type(4)))  float f32x4;
typedef __attribute__((ext_vector_type(8)))  short bf16x8;

__device__ __forceinline__ unsigned int rne_bf16(float f) {
    union { float f; unsigned int u; } v; v.f = f;
    return (v.u + 0x7FFFu + ((v.u >> 16) & 1u)) >> 16;
}
__device__ __forceinline__ float bf16f(unsigned int h) {
    union { float f; unsigned int u; } v; v.u = h << 16;
    return v.f;
}
__device__ __forceinline__ unsigned int f2u(float f) {
    union { float f; unsigned int u; } v; v.f = f; return v.u;
}
__device__ __forceinline__ float u2f(unsigned int u) {
    union { float f; unsigned int u; } v; v.u = u; return v.f;
}

// Pre-kernel: codebook bf16-rounded + sq-norms OF THE ROUNDED rows (dist =
// exact distance between rounded vectors + code-independent offset).
// Fragment-major: index ((c*8+t)*64 + lane), 8 bf16/lane.
__global__ __launch_bounds__(256) void prep_kernel(
        const float* __restrict__ cb, float* __restrict__ ww,
        short* __restrict__ cbh) {
    const int tid = blockIdx.x * 256 + threadIdx.x;   // 0..8191
    if (tid < NK) {
        const float* row = cb + tid * DIM;
        float s = 0.f;
        #pragma unroll 8
        for (int d = 0; d < DIM; ++d) {
            float r = bf16f(rne_bf16(row[d]));
            s = fmaf(r, r, s);
        }
        ww[tid] = s;
    }
    const int l = tid & 63;
    const int t = (tid >> 6) & 7;
    const int c = tid >> 9;
    const float* src = cb + (c * 32 + (l & 31)) * DIM + t * 16 + ((l >> 5) << 3);
    bf16x8 vh;
    #pragma unroll
    for (int j = 0; j < 8; ++j) vh[j] = (short)rne_bf16(src[j]);
    ((bf16x8*)cbh)[tid] = vh;
}

// One wave per block: 32 rows x 512 cols. Zero __syncthreads (wave-synchronous).
// Grid 4096 at 2 waves/SIMD -> 8 blocks/CU resident, 16 total/CU = 2
// generations -> cross-generation phase overlap (read mixes under write wall).
__global__ __launch_bounds__(64, 2) void vq_main(
        const float* __restrict__ x, const float* __restrict__ cb,
        const float* __restrict__ ww,
        const short* __restrict__ cbh,
        float* __restrict__ out, float* __restrict__ partials) {
    __shared__ int idx_s[32];

    const int lane  = threadIdx.x;         // 0..63
    const int bid   = blockIdx.x;
    const int bb    = bid >> 10;           // 1024 blocks per batch elem
    const int srel  = (bid & 1023) << 5;   // 32 spatial per block
    const int hi4   = (lane >> 5) << 2;
    const int row32 = lane & 31;
    const int kb    = (lane >> 5) << 3;    // k-offset 0 or 8

    const float* xrow = x + (size_t)bb * (DIM * SPB) + srel + row32;

    // ---- phase 1: direct global fragment loads (nt) + bf16 round + true norm
    bf16x8 ah[8];
    float xxl = 0.f;
    #pragma unroll
    for (int t = 0; t < 8; ++t) {
        bf16x8 vh;
        #pragma unroll
        for (int j = 0; j < 8; ++j) {
            float f = __builtin_nontemporal_load(xrow + (size_t)(t * 16 + kb + j) * SPB);
            xxl = fmaf(f, f, xxl);
            vh[j] = (short)rne_bf16(f);
        }
        ah[t] = vh;
    }
    // lane & lane^32 hold complementary k-halves of the same row
    xxl += __shfl_xor(xxl, 32, 64);
    float xxr[16];
    #pragma unroll
    for (int r = 0; r < 16; ++r)
        xxr[r] = __shfl(xxl, (r & 3) + ((r >> 2) << 3) + hi4, 64);

    unsigned int best[16];
    #pragma unroll
    for (int r = 0; r < 16; ++r) best[r] = 0xFFFFFFFFu;

    const size_t drow = (size_t)bid << 5;   // global row base

    // ---- main loop: 16 col-tiles of 32 codes; single-term bf16 MFMA; no barriers
    for (int c = 0; c < 16; ++c) {
        f32x16 acc = {};
        const bf16x8* ph = (const bf16x8*)cbh + c * 512 + lane;
        #pragma unroll
        for (int t = 0; t < 8; ++t) {
            bf16x8 bh = ph[t * 64];
            acc = __builtin_amdgcn_mfma_f32_32x32x16_bf16(ah[t], bh, acc, 0, 0, 0);
        }
        const int kcol = (c << 5) + row32;
        const float wwc = ww[kcol];
        #pragma unroll
        for (int r = 0; r < 16; ++r) {
            float dist = fmaf(-2.f, acc[r], xxr[r] + wwc);
            int rl = (r & 3) + ((r >> 2) << 3) + hi4;
            __builtin_nontemporal_store(dist,
                &out[(size_t)D_OFF + (drow + rl) * NK + kcol]);
            unsigned int pack = (f2u(dist) & ~511u) | (unsigned int)kcol;
            best[r] = pack < best[r] ? pack : best[r];
        }
    }

    // ---- argmin: u32 shuffle-min over each 32-lane column group
    #pragma unroll
    for (int r = 0; r < 16; ++r) {
        unsigned int b = best[r];
        #pragma unroll
        for (int m = 16; m >= 1; m >>= 1) {
            unsigned int ob = __shfl_xor(b, m, 64);
            b = ob < b ? ob : b;
        }
        best[r] = b;
    }
    // lanes 0 and 32 publish the 32 row results (wave-synchronous LDS, no barrier)
    if (row32 == 0) {
        #pragma unroll
        for (int r = 0; r < 16; ++r)
            idx_s[(r & 3) + ((r >> 2) << 3) + hi4] = (int)(best[r] & 511u);
    }

    // ---- loss partial: sum of 16 row-minima per group, + cross-group
    {
        float s = 0.f;
        #pragma unroll
        for (int r = 0; r < 16; ++r) s += u2f(best[r] & ~511u);
        s += __shfl_xor(s, 32, 64);
        if (lane == 0) partials[bid] = s;
    }

    // ---- quantized: gather cb row (L2-hot) to regs, scalar column stores
    {
        int r = lane >> 1, h = lane & 1;
        const float* src = cb + (size_t)idx_s[r] * DIM + h * 64;
        float* ob = out + (size_t)bb * (DIM * SPB) + srel + r;
        #pragma unroll
        for (int q = 0; q < 16; ++q) {
            f32x4 v = *(const f32x4*)(src + (q << 2));
            #pragma unroll
            for (int e = 0; e < 4; ++e) {
                int d = h * 64 + (q << 2) + e;
                __builtin_nontemporal_store(v[e], &ob[(size_t)d * SPB]);
            }
        }
    }

    // ---- encoding one-hot: fused zero+one-hot, 1KB contiguous per instruction
    {
        f32x4* ebase = (f32x4*)(out + (size_t)E_OFF) + ((size_t)bid << 12);
        #pragma unroll
        for (int j = 0; j < 64; ++j) {
            int flat4 = j * 64 + lane;     // 4096 f32x4 per block (32 rows x 512)
            int r   = flat4 >> 7;
            int cb4 = (flat4 & 127) << 2;
            int idxr = idx_s[r];
            f32x4 val;
            val[0] = (idxr == cb4    ) ? 1.0f : 0.0f;
            val[1] = (idxr == cb4 + 1) ? 1.0f : 0.0f;
            val[2] = (idxr == cb4 + 2) ? 1.0f : 0.0f;
            val[3] = (idxr == cb4 + 3) ? 1.0f : 0.0f;
            __builtin_nontemporal_store(val, ebase + flat4);
        }
    }
}

__global__ __launch_bounds__(256) void loss_kernel(const float* __restrict__ partials,
                                                   float* __restrict__ out) {
    __shared__ double sd[256];
    int tid = threadIdx.x;
    double s = 0.0;
    for (int i = tid; i < NBLK; i += 256) s += (double)partials[i];
    sd[tid] = s;
    __syncthreads();
    for (int k = 128; k > 0; k >>= 1) {
        if (tid < k) sd[tid] += sd[tid + k];
        __syncthreads();
    }
    if (tid == 0) out[L_OFF] = (float)(2.0 * sd[0] / 16777216.0);
}

extern "C" void kernel_launch(void* const* d_in, const int* in_sizes, int n_in,
                              void* d_out, int out_size, void* d_ws, size_t ws_size,
                              hipStream_t stream) {
    const float* x  = (const float*)d_in[0];
    const float* cb = (const float*)d_in[1];
    float* out = (float*)d_out;
    char*  ws  = (char*)d_ws;
    float* ww  = (float*)ws;                          // 2048 B
    short* cbh = (short*)(ws + 2048);                 // 131072 B
    float* partials = (float*)(ws + 2048 + 131072);   // 16384 B

    prep_kernel<<<32, 256, 0, stream>>>(cb, ww, cbh);
    vq_main<<<NBLK, 64, 0, stream>>>(x, cb, ww, cbh, out, partials);
    loss_kernel<<<1, 256, 0, stream>>>(partials, out);
}